// Round 11
// baseline (457.188 us; speedup 1.0000x reference)
//
#include <hip/hip_runtime.h>

// Problem constants (from reference setup_inputs): B=128, Q=500, C=80, T=64
#define BN 128
#define QN 500
#define CLS 80
#define TN 64
#define RPB 20                  // rows per producer block
#define CBI 25                  // producer blocks per image (500/20)
#define RPW 5                   // rows per wave (RPB/4), compile-time trip
#define GROUP (CBI + 1)         // 26 blocks/image: 25 producers + 1 consumer

typedef unsigned long long ull;

// Monotonic float->uint map: a < b  <=>  fkey(a) < fkey(b); equal <=> equal
__device__ __forceinline__ unsigned fkey(float x) {
    unsigned u = __float_as_uint(x);
    return (u & 0x80000000u) ? ~u : (u | 0x80000000u);
}
__device__ __forceinline__ ull kmin(ull a, ull b) { return a < b ? a : b; }

// agent-scope relaxed loads: read through the (non-coherent) per-XCD caches.
__device__ __forceinline__ ull aload64(const ull* p) {
    return __hip_atomic_load(p, __ATOMIC_RELAXED, __HIP_MEMORY_SCOPE_AGENT);
}
__device__ __forceinline__ float aloadf(const float* p) {
    unsigned v = __hip_atomic_load((const unsigned*)p, __ATOMIC_RELAXED,
                                   __HIP_MEMORY_SCOPE_AGENT);
    return __uint_as_float(v);
}

// 64-lane u64 min via DPP (row_shr 1/2/4/8 + row_bcast 15/31); identity ~0
// shifts in via old-value. Single 6-step chain; key low bits carry the flat
// index -> u64 min == exact raveled argmin incl. first-occurrence tie-break.
__device__ __forceinline__ ull wave_min_u64(ull k) {
#define STEP(ctrl)                                                            \
    {                                                                         \
        unsigned lo = (unsigned)k, hi = (unsigned)(k >> 32);                  \
        unsigned plo = (unsigned)__builtin_amdgcn_update_dpp(                 \
            (int)0xFFFFFFFF, (int)lo, (ctrl), 0xf, 0xf, false);               \
        unsigned phi = (unsigned)__builtin_amdgcn_update_dpp(                 \
            (int)0xFFFFFFFF, (int)hi, (ctrl), 0xf, 0xf, false);               \
        ull p = ((ull)phi << 32) | plo;                                       \
        k = p < k ? p : k;                                                    \
    }
    STEP(0x111) STEP(0x112) STEP(0x114) STEP(0x118) STEP(0x142) STEP(0x143)
#undef STEP
    unsigned lo = (unsigned)__builtin_amdgcn_readlane((int)(unsigned)k, 63);
    unsigned hi = (unsigned)__builtin_amdgcn_readlane((int)(unsigned)(k >> 32), 63);
    return ((ull)hi << 32) | lo;
}

// ---------------------------------------------------------------------------
// Greedy (single wave; lane = column). m1[j] = min alive key of column j.
// COH=1: all Cmat reads via agent-scope atomics (fused path: data written by
// other blocks in the SAME dispatch -> must bypass stale L1/L2).
// ---------------------------------------------------------------------------
template <int COH>
__device__ __forceinline__ void greedy_loop(
    const float* __restrict__ Cb, ull m1, int b, int lane,
    float* __restrict__ out_rows, float* __restrict__ out_cols)
{
    // row-dead bitmask (wave-uniform, static indices); rows 500..511
    // (rescan over-range, reads stay inside d_out) pre-marked dead.
    ull rowdead[8];
    #pragma unroll
    for (int w = 0; w < 8; ++w) rowdead[w] = 0ull;
    rowdead[7] = 0xFFF0000000000000ull;

    int my_i = 0, my_j = 0;             // lane t captures iteration t's result

    for (int t = 0; t < TN; ++t) {
        const ull best = wave_min_u64(m1);                 // uniform
        const unsigned flat = (unsigned)best;
        const int i = (int)(flat >> 6);
        const int j = (int)(flat & 63u);
        if (lane == t) { my_i = i; my_j = j; }

        if (lane == j) m1 = ~0ull;                         // retire column
        #pragma unroll
        for (int w = 0; w < 8; ++w)                        // retire row
            if ((i >> 6) == w) rowdead[w] |= (1ull << (i & 63));

        // stale champions (argmin row == i) rescan; INF m1 auto-excluded
        // (low32=0xFFFFFFFF -> argrow 0x3FFFFFF never equals i<=511).
        ull need = __ballot((((unsigned)m1) >> 6) == (unsigned)i);
        while (need) {                                     // ~4.6 total/image
            const int jr = (int)(__ffsll((long long)need) - 1);  // lane==column
            need &= need - 1;
            ull nb = ~0ull;
            #pragma unroll
            for (int k8 = 0; k8 < 8; ++k8) {
                int r = lane + (k8 << 6);
                const float* ap = Cb + (size_t)r * TN + jr;
                float vv = COH ? aloadf(ap) : *ap;
                bool dead = (rowdead[k8] >> lane) & 1ull;
                ull kk = dead ? ~0ull
                              : (((ull)fkey(vv) << 32) | (unsigned)(r * TN + jr));
                nb = kmin(nb, kk);
            }
            nb = wave_min_u64(nb);
            if (lane == jr) m1 = nb;
        }
    }

    out_rows[b * TN + lane] = (float)my_i;                 // coalesced
    out_cols[b * TN + lane] = (float)my_j;
}

// ---------------------------------------------------------------------------
// FUSED producer/consumer kernel. blockIdx = g*26 + r:
//  r < 25: producer (b=g, rows [r*20, r*20+20)) -- cost math BYTE-IDENTICAL
//    to rounds 4/6/8/9/10 (expf, log1pf, logf, true divisions; fast-math
//    flips greedy ties -> round-5 failure). Ends with threadfence (agent
//    release, flushes Cmat from XCD L2) + release-store of 64 colmin keys.
//  r == 25: consumer (b=g) -- spins (relaxed agent loads + s_sleep) until
//    all 25 partial rows lose their 0xAA poison (real keys: low32 < 32000),
//    acquire-fences, merges, runs greedy. <=128 spinners vs >=1024 resident
//    block slots -> no deadlock regardless of dispatch order.
// ---------------------------------------------------------------------------
__global__ __launch_bounds__(256) void pc_kernel(
    const float* __restrict__ logits,   // [B,Q,C]
    const float* __restrict__ boxes,    // [B,Q,4]
    const int*   __restrict__ ids,      // [B,T]
    const float* __restrict__ tboxes,   // [B,T,4]
    const float* __restrict__ img,      // [B,4]
    float* __restrict__ Cout,           // [B,Q,T]
    ull* __restrict__ partial,          // [B,CBI,TN] colmin keys (ws, 0xAA-poisoned)
    float* __restrict__ out_rows,       // [B,T]
    float* __restrict__ out_cols)       // [B,T]
{
    const int b    = blockIdx.x / GROUP;
    const int role = blockIdx.x % GROUP;
    const int wave = threadIdx.x >> 6;
    const int lane = threadIdx.x & 63;   // = column t

    __shared__ ull pk[4][TN];            // producer merge / consumer merge

    if (role < CBI) {
        // ---------------- producer ----------------
        const int q0 = role * RPB + wave * RPW;

        const float4 tb = *(const float4*)(tboxes + (size_t)(b * TN + lane) * 4);
        const float4 im = *(const float4*)(img + b * 4);
        const int    id = ids[b * TN + lane];
        const float tnx = tb.x / im.x, tny = tb.y / im.y;
        const float tnz = tb.z / im.z, tnw = tb.w / im.w;
        const float area_b = (tb.z - tb.x) * (tb.w - tb.y);

        ull colmin = ~0ull;
        #pragma unroll
        for (int rr = 0; rr < RPW; ++rr) {
            const int q = q0 + rr;
            const float4 pb = *(const float4*)(boxes + (size_t)(b * QN + q) * 4);
            const float x   = logits[(size_t)(b * QN + q) * CLS + id];

            float prob = 1.0f / (1.0f + expf(-x));
            float neg  = 0.75f * (prob * prob) * (-log1pf(1e-8f - prob));
            float pos  = 0.25f * ((1.0f - prob) * (1.0f - prob)) * (-logf(prob + 1e-8f));
            float cls  = pos - neg;

            float l1 = fabsf(pb.x / im.x - tnx) + fabsf(pb.y / im.y - tny)
                     + fabsf(pb.z / im.z - tnz) + fabsf(pb.w / im.w - tnw);

            float area_a = (pb.z - pb.x) * (pb.w - pb.y);
            float ltx = fmaxf(pb.x, tb.x), lty = fmaxf(pb.y, tb.y);
            float rbx = fminf(pb.z, tb.z), rby = fminf(pb.w, tb.w);
            float iw = fmaxf(rbx - ltx, 0.0f), ih = fmaxf(rby - lty, 0.0f);
            float inter = iw * ih;
            float uni   = area_a + area_b - inter;
            float iou   = inter / uni;
            float ex1 = fminf(pb.x, tb.x), ey1 = fminf(pb.y, tb.y);
            float ex2 = fmaxf(pb.z, tb.z), ey2 = fmaxf(pb.w, tb.w);
            float ew = fmaxf(ex2 - ex1, 0.0f), eh = fmaxf(ey2 - ey1, 0.0f);
            float enc = ew * eh;
            float giou = iou - (enc - uni) / enc;

            float cost = 5.0f * l1 + 2.0f * cls + 2.0f * (-giou);
            Cout[(size_t)(b * QN + q) * TN + lane] = cost;
            colmin = kmin(colmin, ((ull)fkey(cost) << 32) | (unsigned)(q * TN + lane));
        }

        pk[wave][lane] = colmin;
        __threadfence();                 // agent release: flush my Cmat stores
        __syncthreads();                 // all waves' fences complete
        if (wave == 0) {
            ull k = kmin(kmin(pk[0][lane], pk[1][lane]),
                         kmin(pk[2][lane], pk[3][lane]));
            __hip_atomic_store(&partial[((size_t)b * CBI + role) * TN + lane], k,
                               __ATOMIC_RELEASE, __HIP_MEMORY_SCOPE_AGENT);
        }
        return;
    }

    // ---------------- consumer ----------------
    const float* Cb = Cout + (size_t)b * QN * TN;
    const ull* pt = partial + (size_t)b * CBI * TN;

    {
        ull k = ~0ull;
        for (int row = wave; row < CBI; row += 4) {   // 6-7 rows per wave
            const ull* slot = &pt[(size_t)row * TN + lane];
            ull v = aload64(slot);
            while ((unsigned)v >= (unsigned)(QN * TN)) {  // poison: low32=0xAAAAAAAA
                __builtin_amdgcn_s_sleep(8);
                v = aload64(slot);
            }
            k = kmin(k, v);
        }
        pk[wave][lane] = k;
    }
    __threadfence();                     // acquire: producers' Cmat now readable
    __syncthreads();
    if (wave != 0) return;

    ull m1 = kmin(kmin(pk[0][lane], pk[1][lane]), kmin(pk[2][lane], pk[3][lane]));
    greedy_loop<1>(Cb, m1, b, lane, out_rows, out_cols);
}

// ---------------------------------------------------------------------------
// Fallback (ws too small; not expected — ws is ~268 MB). Two-kernel round-10
// path: cost-only producer grid + full-scan assign (plain loads are safe
// across the kernel boundary).
// ---------------------------------------------------------------------------
__global__ __launch_bounds__(256) void cost_kernel(
    const float* __restrict__ logits, const float* __restrict__ boxes,
    const int* __restrict__ ids, const float* __restrict__ tboxes,
    const float* __restrict__ img, float* __restrict__ Cout)
{
    const int b    = blockIdx.x / CBI;
    const int blk  = blockIdx.x % CBI;
    const int wave = threadIdx.x >> 6;
    const int lane = threadIdx.x & 63;
    const int q0   = blk * RPB + wave * RPW;

    const float4 tb = *(const float4*)(tboxes + (size_t)(b * TN + lane) * 4);
    const float4 im = *(const float4*)(img + b * 4);
    const int    id = ids[b * TN + lane];
    const float tnx = tb.x / im.x, tny = tb.y / im.y;
    const float tnz = tb.z / im.z, tnw = tb.w / im.w;
    const float area_b = (tb.z - tb.x) * (tb.w - tb.y);

    #pragma unroll
    for (int rr = 0; rr < RPW; ++rr) {
        const int q = q0 + rr;
        const float4 pb = *(const float4*)(boxes + (size_t)(b * QN + q) * 4);
        const float x   = logits[(size_t)(b * QN + q) * CLS + id];
        float prob = 1.0f / (1.0f + expf(-x));
        float neg  = 0.75f * (prob * prob) * (-log1pf(1e-8f - prob));
        float pos  = 0.25f * ((1.0f - prob) * (1.0f - prob)) * (-logf(prob + 1e-8f));
        float cls  = pos - neg;
        float l1 = fabsf(pb.x / im.x - tnx) + fabsf(pb.y / im.y - tny)
                 + fabsf(pb.z / im.z - tnz) + fabsf(pb.w / im.w - tnw);
        float area_a = (pb.z - pb.x) * (pb.w - pb.y);
        float ltx = fmaxf(pb.x, tb.x), lty = fmaxf(pb.y, tb.y);
        float rbx = fminf(pb.z, tb.z), rby = fminf(pb.w, tb.w);
        float iw = fmaxf(rbx - ltx, 0.0f), ih = fmaxf(rby - lty, 0.0f);
        float inter = iw * ih;
        float uni   = area_a + area_b - inter;
        float iou   = inter / uni;
        float ex1 = fminf(pb.x, tb.x), ey1 = fminf(pb.y, tb.y);
        float ex2 = fmaxf(pb.z, tb.z), ey2 = fmaxf(pb.w, tb.w);
        float ew = fmaxf(ex2 - ex1, 0.0f), eh = fmaxf(ey2 - ey1, 0.0f);
        float enc = ew * eh;
        float giou = iou - (enc - uni) / enc;
        Cout[(size_t)(b * QN + q) * TN + lane] = 5.0f * l1 + 2.0f * cls + 2.0f * (-giou);
    }
}

__global__ __launch_bounds__(512, 1) void assign_scan_kernel(
    const float* __restrict__ Cmat,
    float* __restrict__ out_rows, float* __restrict__ out_cols)
{
    const int b    = blockIdx.x;
    const int wave = threadIdx.x >> 6;
    const int lane = threadIdx.x & 63;
    const float* Cb = Cmat + (size_t)b * QN * TN;

    __shared__ ull smin[32][TN];
    {
        const int g  = lane >> 4;
        const int c4 = (lane & 15) << 2;
        const int rbeg = wave * 63 + g;
        ull mc0 = ~0ull, mc1 = ~0ull, mc2 = ~0ull, mc3 = ~0ull;
        #pragma unroll
        for (int k = 0; k < 16; ++k) {
            const int r = rbeg + 4 * k;            // <= 504: inside d_out
            const float4 v = *(const float4*)(Cb + (size_t)r * TN + c4);
            const bool ok = (r < QN);
            const unsigned fb = (unsigned)(r * TN + c4);
            mc0 = kmin(mc0, ok ? (((ull)fkey(v.x) << 32) | (fb + 0)) : ~0ull);
            mc1 = kmin(mc1, ok ? (((ull)fkey(v.y) << 32) | (fb + 1)) : ~0ull);
            mc2 = kmin(mc2, ok ? (((ull)fkey(v.z) << 32) | (fb + 2)) : ~0ull);
            mc3 = kmin(mc3, ok ? (((ull)fkey(v.w) << 32) | (fb + 3)) : ~0ull);
        }
        const int lrow = (wave << 2) | g;
        smin[lrow][c4 + 0] = mc0; smin[lrow][c4 + 1] = mc1;
        smin[lrow][c4 + 2] = mc2; smin[lrow][c4 + 3] = mc3;
    }
    __syncthreads();
    if (wave != 0) return;
    ull m1 = ~0ull;
    #pragma unroll
    for (int w = 0; w < 32; ++w) m1 = kmin(m1, smin[w][lane]);
    greedy_loop<0>(Cb, m1, b, lane, out_rows, out_cols);
}

extern "C" void kernel_launch(void* const* d_in, const int* in_sizes, int n_in,
                              void* d_out, int out_size, void* d_ws, size_t ws_size,
                              hipStream_t stream) {
    const float* logits = (const float*)d_in[0];   // [128,500,80]
    const float* boxes  = (const float*)d_in[1];   // [128,500,4]
    const int*   ids    = (const int*)d_in[2];     // [128,64]
    const float* tboxes = (const float*)d_in[3];   // [128,64,4]
    const float* img    = (const float*)d_in[4];   // [128,4]

    float* out  = (float*)d_out;
    float* Cmat = out;                              // 128*500*64 = 4,096,000
    float* rows = out + (size_t)BN * QN * TN;       // +8192
    float* cols = rows + BN * TN;                   // +8192

    const size_t table_bytes = (size_t)BN * CBI * TN * sizeof(ull);  // 1.6 MB
    if (ws_size >= table_bytes) {
        // fused producer/consumer: relies on the harness 0xAA-poison of d_ws
        // as the "not yet written" marker (real keys have low32 < 32000).
        pc_kernel<<<BN * GROUP, 256, 0, stream>>>(logits, boxes, ids, tboxes, img,
                                                  Cmat, (ull*)d_ws, rows, cols);
    } else {
        cost_kernel<<<BN * CBI, 256, 0, stream>>>(logits, boxes, ids, tboxes, img, Cmat);
        assign_scan_kernel<<<BN, 512, 0, stream>>>(Cmat, rows, cols);
    }
}

// Round 12
// 145.361 us; speedup vs baseline: 3.1452x; 3.1452x over previous
//
#include <hip/hip_runtime.h>

// Problem constants (from reference setup_inputs): B=128, Q=500, C=80, T=64
#define BN 128
#define QN 500
#define CLS 80
#define TN 64
#define RPB 20                  // rows per cost block
#define CBI 25                  // cost blocks per image (500/20)
#define RPW 5                   // rows per wave (RPB/4), compile-time trip

typedef unsigned long long ull;

// Monotonic float->uint map: a < b  <=>  fkey(a) < fkey(b); equal <=> equal
__device__ __forceinline__ unsigned fkey(float x) {
    unsigned u = __float_as_uint(x);
    return (u & 0x80000000u) ? ~u : (u | 0x80000000u);
}
__device__ __forceinline__ ull kmin(ull a, ull b) { return a < b ? a : b; }  // branchless

// 64-lane u64 min via DPP (row_shr 1/2/4/8 + row_bcast 15/31); identity ~0
// fed to invalid lanes via old-value. Key low bits carry the flat index ->
// u64 min == exact raveled argmin incl. first-occurrence tie-break.
// Correctness-verified in round 11 (passed, absmax 0.0625).
__device__ __forceinline__ ull wave_min_u64(ull k) {
#define STEP(ctrl)                                                            \
    {                                                                         \
        unsigned lo = (unsigned)k, hi = (unsigned)(k >> 32);                  \
        unsigned plo = (unsigned)__builtin_amdgcn_update_dpp(                 \
            (int)0xFFFFFFFF, (int)lo, (ctrl), 0xf, 0xf, false);               \
        unsigned phi = (unsigned)__builtin_amdgcn_update_dpp(                 \
            (int)0xFFFFFFFF, (int)hi, (ctrl), 0xf, 0xf, false);               \
        ull p = ((ull)phi << 32) | plo;                                       \
        k = p < k ? p : k;                                                    \
    }
    STEP(0x111) STEP(0x112) STEP(0x114) STEP(0x118) STEP(0x142) STEP(0x143)
#undef STEP
    unsigned lo = (unsigned)__builtin_amdgcn_readlane((int)(unsigned)k, 63);
    unsigned hi = (unsigned)__builtin_amdgcn_readlane((int)(unsigned)(k >> 32), 63);
    return ((ull)hi << 32) | lo;
}

// ---------------------------------------------------------------------------
// Kernel 1: cost matrix — per-element math BYTE-IDENTICAL to rounds 4/6/8-10
// (expf, log1pf, logf, true divisions; fast-math flips greedy ties -> round-5
// failure). Wave owns RPW=5 rows, compile-time trip -> 5 gathers in flight.
// Block emits 64 colmin keys via PLAIN store into its own partial slot
// (no atomics, no init kernel; kernel boundary provides coherence --
// round 11 proved in-dispatch cross-XCD coupling costs 3x the whole budget).
// ---------------------------------------------------------------------------
__global__ __launch_bounds__(256) void cost_kernel(
    const float* __restrict__ logits,   // [B,Q,C]
    const float* __restrict__ boxes,    // [B,Q,4]
    const int*   __restrict__ ids,      // [B,T]
    const float* __restrict__ tboxes,   // [B,T,4]
    const float* __restrict__ img,      // [B,4]
    float* __restrict__ Cout,           // [B,Q,T]
    ull* __restrict__ partial)          // [B*CBI, 64] colmin keys, or null
{
    const int b    = blockIdx.x / CBI;
    const int blk  = blockIdx.x % CBI;
    const int wave = threadIdx.x >> 6;
    const int lane = threadIdx.x & 63;   // = column t
    const int q0   = blk * RPB + wave * RPW;

    const float4 tb = *(const float4*)(tboxes + (size_t)(b * TN + lane) * 4);
    const float4 im = *(const float4*)(img + b * 4);
    const int    id = ids[b * TN + lane];
    const float tnx = tb.x / im.x, tny = tb.y / im.y;
    const float tnz = tb.z / im.z, tnw = tb.w / im.w;
    const float area_b = (tb.z - tb.x) * (tb.w - tb.y);

    ull colmin = ~0ull;
    #pragma unroll
    for (int rr = 0; rr < RPW; ++rr) {
        const int q = q0 + rr;
        const float4 pb = *(const float4*)(boxes + (size_t)(b * QN + q) * 4);
        const float x   = logits[(size_t)(b * QN + q) * CLS + id];

        float prob = 1.0f / (1.0f + expf(-x));
        float neg  = 0.75f * (prob * prob) * (-log1pf(1e-8f - prob));
        float pos  = 0.25f * ((1.0f - prob) * (1.0f - prob)) * (-logf(prob + 1e-8f));
        float cls  = pos - neg;

        float l1 = fabsf(pb.x / im.x - tnx) + fabsf(pb.y / im.y - tny)
                 + fabsf(pb.z / im.z - tnz) + fabsf(pb.w / im.w - tnw);

        float area_a = (pb.z - pb.x) * (pb.w - pb.y);
        float ltx = fmaxf(pb.x, tb.x), lty = fmaxf(pb.y, tb.y);
        float rbx = fminf(pb.z, tb.z), rby = fminf(pb.w, tb.w);
        float iw = fmaxf(rbx - ltx, 0.0f), ih = fmaxf(rby - lty, 0.0f);
        float inter = iw * ih;
        float uni   = area_a + area_b - inter;
        float iou   = inter / uni;
        float ex1 = fminf(pb.x, tb.x), ey1 = fminf(pb.y, tb.y);
        float ex2 = fmaxf(pb.z, tb.z), ey2 = fmaxf(pb.w, tb.w);
        float ew = fmaxf(ex2 - ex1, 0.0f), eh = fmaxf(ey2 - ey1, 0.0f);
        float enc = ew * eh;
        float giou = iou - (enc - uni) / enc;

        float cost = 5.0f * l1 + 2.0f * cls + 2.0f * (-giou);
        Cout[(size_t)(b * QN + q) * TN + lane] = cost;
        colmin = kmin(colmin, ((ull)fkey(cost) << 32) | (unsigned)(q * TN + lane));
    }

    if (partial) {
        __shared__ ull pk[4][TN];
        pk[wave][lane] = colmin;
        __syncthreads();
        if (wave == 0) {
            ull k = kmin(kmin(pk[0][lane], pk[1][lane]),
                         kmin(pk[2][lane], pk[3][lane]));
            partial[(size_t)blockIdx.x * TN + lane] = k;   // own slot: no race
        }
    }
}

// ---------------------------------------------------------------------------
// Greedy hot loop (single wave; lane = column). m1[j] = min alive key of
// column j. Per iteration: ONE 6-step u64 DPP reduce (exact raveled argmin
// incl. first-occurrence tie-break). Champion-row death -> cooperative
// column rescan (expected ~4.6 per image). Plain loads: data written by a
// PREVIOUS kernel -> kernel boundary flushed caches.
// ---------------------------------------------------------------------------
__device__ __forceinline__ void greedy_loop(
    const float* __restrict__ Cb, ull m1, int b, int lane,
    float* __restrict__ out_rows, float* __restrict__ out_cols)
{
    // row-dead bitmask (wave-uniform, static indices); rows 500..511
    // (rescan over-range, reads stay inside d_out) pre-marked dead.
    ull rowdead[8];
    #pragma unroll
    for (int w = 0; w < 8; ++w) rowdead[w] = 0ull;
    rowdead[7] = 0xFFF0000000000000ull;

    int my_i = 0, my_j = 0;             // lane t captures iteration t's result

    for (int t = 0; t < TN; ++t) {
        const ull best = wave_min_u64(m1);                 // uniform
        const unsigned flat = (unsigned)best;
        const int i = (int)(flat >> 6);
        const int j = (int)(flat & 63u);
        if (lane == t) { my_i = i; my_j = j; }

        if (lane == j) m1 = ~0ull;                         // retire column
        #pragma unroll
        for (int w = 0; w < 8; ++w)                        // retire row
            if ((i >> 6) == w) rowdead[w] |= (1ull << (i & 63));

        // stale champions (argmin row == i) rescan; INF m1 auto-excluded
        // (low32=0xFFFFFFFF -> argrow 0x3FFFFFF never equals i<=511).
        ull need = __ballot((((unsigned)m1) >> 6) == (unsigned)i);
        while (need) {                                     // ~4.6 total/image
            const int jr = (int)(__ffsll((long long)need) - 1);  // lane==column
            need &= need - 1;
            ull nb = ~0ull;
            #pragma unroll
            for (int k8 = 0; k8 < 8; ++k8) {
                int r = lane + (k8 << 6);
                float vv = Cb[(size_t)r * TN + jr];
                bool dead = (rowdead[k8] >> lane) & 1ull;
                ull kk = dead ? ~0ull
                              : (((ull)fkey(vv) << 32) | (unsigned)(r * TN + jr));
                nb = kmin(nb, kk);
            }
            nb = wave_min_u64(nb);
            if (lane == jr) m1 = nb;
        }
    }

    out_rows[b * TN + lane] = (float)my_i;                 // coalesced
    out_cols[b * TN + lane] = (float)my_j;
}

// Table path: 512 threads; 8 waves cooperatively reduce the image's 25
// partial rows (coalesced 512 B row loads), LDS merge, wave 0 runs greedy.
__global__ __launch_bounds__(512, 1) void assign_table_kernel(
    const float* __restrict__ Cmat, const ull* __restrict__ partial,
    float* __restrict__ out_rows, float* __restrict__ out_cols)
{
    const int b    = blockIdx.x;
    const int wave = threadIdx.x >> 6;
    const int lane = threadIdx.x & 63;
    const float* Cb = Cmat + (size_t)b * QN * TN;
    const ull* pt = partial + (size_t)b * CBI * TN;

    __shared__ ull smin[8][TN];         // 4 KB
    {
        ull k = ~0ull;
        #pragma unroll
        for (int p = 0; p < 4; ++p) {   // rows wave, wave+8, wave+16, wave+24
            const int row = wave + 8 * p;
            if (row < CBI) k = kmin(k, pt[(size_t)row * TN + lane]);
        }
        smin[wave][lane] = k;
    }
    __syncthreads();
    if (wave != 0) return;

    ull m1 = ~0ull;
    #pragma unroll
    for (int w = 0; w < 8; ++w) m1 = kmin(m1, smin[w][lane]);

    greedy_loop(Cb, m1, b, lane, out_rows, out_cols);
}

// Fallback path (no workspace): float4 init, branchless min, LDS merge.
// Wave w, lane l: g=l>>4 owns rows w*63+g+4k (k<16), c4=l&15 owns cols
// [4c4,4c4+4) -> 16 independent float4 loads/thread. Proven in round 9.
__global__ __launch_bounds__(512, 1) void assign_scan_kernel(
    const float* __restrict__ Cmat,
    float* __restrict__ out_rows, float* __restrict__ out_cols)
{
    const int b    = blockIdx.x;
    const int wave = threadIdx.x >> 6;
    const int lane = threadIdx.x & 63;
    const float* Cb = Cmat + (size_t)b * QN * TN;

    __shared__ ull smin[32][TN];        // 16 KB

    {
        const int g  = lane >> 4;
        const int c4 = (lane & 15) << 2;
        const int rbeg = wave * 63 + g;
        ull mc0 = ~0ull, mc1 = ~0ull, mc2 = ~0ull, mc3 = ~0ull;
        #pragma unroll
        for (int k = 0; k < 16; ++k) {
            const int r = rbeg + 4 * k;            // <= 504: inside d_out
            const float4 v = *(const float4*)(Cb + (size_t)r * TN + c4);
            const bool ok = (r < QN);
            const unsigned fb = (unsigned)(r * TN + c4);
            mc0 = kmin(mc0, ok ? (((ull)fkey(v.x) << 32) | (fb + 0)) : ~0ull);
            mc1 = kmin(mc1, ok ? (((ull)fkey(v.y) << 32) | (fb + 1)) : ~0ull);
            mc2 = kmin(mc2, ok ? (((ull)fkey(v.z) << 32) | (fb + 2)) : ~0ull);
            mc3 = kmin(mc3, ok ? (((ull)fkey(v.w) << 32) | (fb + 3)) : ~0ull);
        }
        const int lrow = (wave << 2) | g;
        smin[lrow][c4 + 0] = mc0; smin[lrow][c4 + 1] = mc1;
        smin[lrow][c4 + 2] = mc2; smin[lrow][c4 + 3] = mc3;
    }
    __syncthreads();
    if (wave != 0) return;

    ull m1 = ~0ull;
    #pragma unroll
    for (int w = 0; w < 32; ++w) m1 = kmin(m1, smin[w][lane]);

    greedy_loop(Cb, m1, b, lane, out_rows, out_cols);
}

extern "C" void kernel_launch(void* const* d_in, const int* in_sizes, int n_in,
                              void* d_out, int out_size, void* d_ws, size_t ws_size,
                              hipStream_t stream) {
    const float* logits = (const float*)d_in[0];   // [128,500,80]
    const float* boxes  = (const float*)d_in[1];   // [128,500,4]
    const int*   ids    = (const int*)d_in[2];     // [128,64]
    const float* tboxes = (const float*)d_in[3];   // [128,64,4]
    const float* img    = (const float*)d_in[4];   // [128,4]

    float* out  = (float*)d_out;
    float* Cmat = out;                              // 128*500*64 = 4,096,000
    float* rows = out + (size_t)BN * QN * TN;       // +8192
    float* cols = rows + BN * TN;                   // +8192

    const size_t table_bytes = (size_t)BN * CBI * TN * sizeof(ull);  // 1.6 MB
    const bool use_table = (ws_size >= table_bytes);                  // host-constant
    ull* partial = use_table ? (ull*)d_ws : nullptr;

    cost_kernel<<<BN * CBI, 256, 0, stream>>>(logits, boxes, ids, tboxes, img,
                                              Cmat, partial);

    if (use_table)
        assign_table_kernel<<<BN, 512, 0, stream>>>(Cmat, partial, rows, cols);
    else
        assign_scan_kernel<<<BN, 512, 0, stream>>>(Cmat, rows, cols);
}